// Round 2
// baseline (266.733 us; speedup 1.0000x reference)
//
#include <hip/hip_runtime.h>

// Causal linear attention (elu+1 feature map), chunked-scan formulation.
// Shapes fixed by the reference: N=2, L=2048, H=8, D=64, M=64, fp32.
//
// R13 (from R12 @84.5us): single-kernel fusion. The timed iteration is
// dominated by a fixed ~44us harness ws-poison fill; the controllable part
// is our 3 kernels + 2 launch gaps + per-kernel fixed costs. Fuse
// chunksum -> scan -> out into ONE launch with two in-kernel grid barriers
// (monotonic-ticket barrier on a zero-init __device__ global; robust across
// hipGraph replays, no init kernel, device-scope fences for cross-XCD
// coherence). Wins: 2 launch gaps + 2 kernel fixed costs gone; K/V staged
// into LDS once (out-phase reuses Kb/Vt: -16.8 MB HBM re-reads, no second
// phi(K) pass); Q staged in phase 1 so scan+barrier hide it; St/kpref loads
// issue post-barrier-2 and hide under QK^T.
// Co-residency: 512 blocks, 45 KB LDS, __launch_bounds__(256,2) ->
// >=2 blocks/CU * 256 CU = 512 resident. Guaranteed.

namespace {
constexpr int N_ = 2, L_ = 2048, H_ = 8, D_ = 64, M_ = 64;
constexpr int C  = 64;            // chunk length
constexpr int G  = L_ / C;        // 32 chunks per sequence
constexpr int NH = N_ * H_;       // 16 independent (n,h) sequences
constexpr int LDH = H_ * D_;      // stride (floats) between consecutive l
constexpr int TS  = 72;           // bf16 LDS row stride
constexpr int NBLK = NH * G;      // 512 blocks (power of two)
constexpr float EPS_ = 1e-6f;
}

typedef __attribute__((ext_vector_type(8))) short short8;
typedef __attribute__((ext_vector_type(4))) float f32x4;

__device__ __forceinline__ float phi(float x) {
    return x > 0.0f ? x + 1.0f : __expf(x);
}
__device__ __forceinline__ unsigned short f2bf(float x) {
    unsigned int u = __float_as_uint(x);
    u += 0x7fffu + ((u >> 16) & 1u);          // round-to-nearest-even
    return (unsigned short)(u >> 16);
}
__device__ __forceinline__ float bf2f(unsigned short h) {
    return __uint_as_float(((unsigned int)h) << 16);
}
__device__ __forceinline__ ushort4 pack4(float a, float b, float c, float d) {
    ushort4 p; p.x = f2bf(a); p.y = f2bf(b); p.z = f2bf(c); p.w = f2bf(d);
    return p;
}

// ---------------------------------------------------------------------------
// Monotonic-ticket grid barrier. g_bar is zero-initialized at module load and
// only ever increments; barrier instance k admits tickets [512k, 512k+512) and
// releases when the count reaches 512(k+1). Works across any number of
// launches / graph replays (launches are stream-serialized). Device-scope
// atomics + __threadfence() handle cross-XCD L2 writeback / L1 invalidate.
// ---------------------------------------------------------------------------
__device__ unsigned int g_bar = 0;

__device__ __forceinline__ void grid_barrier() {
    __threadfence();                      // release: drain + L2 writeback
    __syncthreads();
    if (threadIdx.x == 0) {
        const unsigned ticket = atomicAdd(&g_bar, 1u);
        const unsigned target = (ticket & ~(unsigned)(NBLK - 1)) + (unsigned)NBLK;
        while (__hip_atomic_load(&g_bar, __ATOMIC_RELAXED,
                                 __HIP_MEMORY_SCOPE_AGENT) < target)
            __builtin_amdgcn_s_sleep(2);
    }
    __syncthreads();
    __threadfence();                      // acquire: L1 invalidate
}

// ---------------------------------------------------------------------------
// Fused kernel: P1 chunk-sums (MFMA) -> B1 -> P2 prefix scan -> B2 ->
// P3 output (MFMA). Block (nh,g) owns chunk g of sequence nh throughout;
// Kb/Vt/Qb staged once in P1 and reused in P3.
// ---------------------------------------------------------------------------
__global__ __launch_bounds__(256, 2) void k_fused(
    const float* __restrict__ queries, const float* __restrict__ keys,
    const float* __restrict__ values, float* __restrict__ out,
    unsigned short* __restrict__ wsSb, float* __restrict__ wsK)
{
    __shared__ __align__(16) unsigned short Kt[C * TS];   // phi(K)^T  (P1)
    __shared__ __align__(16) unsigned short Vt[C * TS];   // V^T       (P1+P3)
    __shared__ __align__(16) unsigned short Qb[C * TS];   // phi(Q)    (P3)
    __shared__ __align__(16) unsigned short Kb[C * TS];   // phi(K)->A (P3)
    __shared__ __align__(16) unsigned short St[C * TS];   // S^T prefix(P3)

    const int bid = blockIdx.x;
    const int g = bid % G, nh = bid / G;
    const int n = nh / H_, h = nh % H_;
    const int t = threadIdx.x;
    const size_t base = ((size_t)(n * L_ + g * C) * H_ + h) * D_;

    // ---- P1 stage: Kt (scatter), Kb/Qb (row-major packed), Vt (scatter) ---
#pragma unroll
    for (int r = 0; r < 4; ++r) {
        const int f = t + 256 * r;
        const int j = f >> 4, c = (f & 15) * 4;
        const size_t ga = base + (size_t)j * LDH + c;
        const float4 kv = *(const float4*)(keys + ga);
        const float4 vv = *(const float4*)(values + ga);
        const float4 qv = *(const float4*)(queries + ga);
        const unsigned short b0 = f2bf(phi(kv.x)), b1 = f2bf(phi(kv.y));
        const unsigned short b2 = f2bf(phi(kv.z)), b3 = f2bf(phi(kv.w));
        Kt[(c + 0) * TS + j] = b0;
        Kt[(c + 1) * TS + j] = b1;
        Kt[(c + 2) * TS + j] = b2;
        Kt[(c + 3) * TS + j] = b3;
        ushort4 pk; pk.x = b0; pk.y = b1; pk.z = b2; pk.w = b3;
        *(ushort4*)&Kb[j * TS + c] = pk;
        *(ushort4*)&Qb[j * TS + c] = pack4(phi(qv.x), phi(qv.y), phi(qv.z), phi(qv.w));
        Vt[(c + 0) * TS + j] = f2bf(vv.x);
        Vt[(c + 1) * TS + j] = f2bf(vv.y);
        Vt[(c + 2) * TS + j] = f2bf(vv.z);
        Vt[(c + 3) * TS + j] = f2bf(vv.w);
    }
    __syncthreads();

    const int w = t >> 6, lane = t & 63;
    const int row16 = lane & 15, quad = lane >> 4;

    // ---- P1 MFMA: S_chunk^T[m][d] (bf16) and ksum[d] (fp32) ---------------
    {
        f32x4 acc[4] = {f32x4{0,0,0,0}, f32x4{0,0,0,0}, f32x4{0,0,0,0}, f32x4{0,0,0,0}};
        f32x4 accK = f32x4{0,0,0,0};
        short8 ones;
#pragma unroll
        for (int i = 0; i < 8; ++i) ones[i] = (short)0x3F80;   // bf16(1.0)

#pragma unroll
        for (int kt = 0; kt < 2; ++kt) {
            const short8 a = *(const short8*)&Kt[(16 * w + row16) * TS + quad * 8 + 32 * kt];
#pragma unroll
            for (int c = 0; c < 4; ++c) {
                const short8 b = *(const short8*)&Vt[(16 * c + row16) * TS + quad * 8 + 32 * kt];
                acc[c] = __builtin_amdgcn_mfma_f32_16x16x32_bf16(a, b, acc[c], 0, 0, 0);
            }
            accK = __builtin_amdgcn_mfma_f32_16x16x32_bf16(a, ones, accK, 0, 0, 0);
        }

        unsigned short* Sc = wsSb + (size_t)bid * (D_ * M_);
#pragma unroll
        for (int c = 0; c < 4; ++c) {
            *(ushort4*)(Sc + (16 * c + row16) * D_ + 16 * w + quad * 4) =
                pack4(acc[c][0], acc[c][1], acc[c][2], acc[c][3]);
        }
        if (row16 == 0) {
#pragma unroll
            for (int r = 0; r < 4; ++r)
                wsK[(size_t)bid * D_ + 16 * w + quad * 4 + r] = accK[r];
        }
    }

    grid_barrier();   // B1: all chunk-sums visible

    // ---- P2: exclusive prefix scans, spread over the whole grid -----------
    // S chains: 32768 uint chains (2 bf16 each), 64 per block on wave 0.
    if (t < 64) {
        const int cid = bid * 64 + t;              // 0..32767
        const int snh = cid >> 11;                 // 2048 chains per nh
        const int off = cid & 2047;
        unsigned int* basep = (unsigned int*)wsSb + (size_t)snh * (G * D_ * M_ / 2) + off;
        float r0 = 0.f, r1 = 0.f;
#pragma unroll
        for (int gg = 0; gg < G; ++gg) {
            unsigned int* p = basep + (size_t)gg * (D_ * M_ / 2);
            const unsigned int v = *p;
            const float v0 = bf2f((unsigned short)(v & 0xffffu));
            const float v1 = bf2f((unsigned short)(v >> 16));
            *p = ((unsigned int)f2bf(r1) << 16) | (unsigned int)f2bf(r0);
            r0 += v0; r1 += v1;
        }
    } else if (bid < NH && t < 128) {
        // ksum chains: 16 nh x 64 d, on wave 1 of blocks 0..15
        const int d = t - 64;
        float rk = 0.f;
        float* kb = wsK + (size_t)bid * (G * D_) + d;
#pragma unroll
        for (int gg = 0; gg < G; ++gg) {
            float* p = kb + (size_t)gg * D_;
            const float v = *p;
            *p = rk;
            rk += v;
        }
    }

    grid_barrier();   // B2: all prefixes visible

    // ---- P3: A = tril(phiQ phiK^T); Z via MFMA; out = (A V + Q Sp) Z ------
    const unsigned short* Spb = wsSb + (size_t)bid * (D_ * M_);
    const float* kpref = wsK + (size_t)bid * D_;

    // St -> regs early (latency hides under QK^T below)
    const int m0 = t >> 3, dg0 = (t & 7) * 8;
    const int i1 = t + 256;
    const int m1 = i1 >> 3, dg1 = (i1 & 7) * 8;
    const short8 s0 = *(const short8*)(Spb + m0 * D_ + dg0);
    const short8 s1 = *(const short8*)(Spb + m1 * D_ + dg1);

    // kpref B-fragments (column-constant): B[k][*] = kpref[k]; hi+lo bf16
    // split keeps fp32-grade precision through the bf16 MFMA.
    const float* kp0 = kpref + quad * 8;
    const float4 kfa = *(const float4*)(kp0);
    const float4 kfb = *(const float4*)(kp0 + 4);
    const float4 kfc = *(const float4*)(kp0 + 32);
    const float4 kfd = *(const float4*)(kp0 + 36);
    short8 bZhi0, bZhi1, bZlo0, bZlo1;
    {
        const float f0[8] = {kfa.x, kfa.y, kfa.z, kfa.w, kfb.x, kfb.y, kfb.z, kfb.w};
        const float f1[8] = {kfc.x, kfc.y, kfc.z, kfc.w, kfd.x, kfd.y, kfd.z, kfd.w};
#pragma unroll
        for (int i = 0; i < 8; ++i) {
            const unsigned short h0 = f2bf(f0[i]);
            bZhi0[i] = (short)h0;
            bZlo0[i] = (short)f2bf(f0[i] - bf2f(h0));
            const unsigned short h1 = f2bf(f1[i]);
            bZhi1[i] = (short)h1;
            bZlo1[i] = (short)f2bf(f1[i] - bf2f(h1));
        }
    }

    // QK^T: wave w -> rows 16w..16w+15, all 4 col-tiles (Qb/Kb from P1)
    short8 aq[2];
#pragma unroll
    for (int kt = 0; kt < 2; ++kt)
        aq[kt] = *(const short8*)&Qb[(16 * w + row16) * TS + quad * 8 + 32 * kt];

    f32x4 accA[4] = {f32x4{0,0,0,0}, f32x4{0,0,0,0}, f32x4{0,0,0,0}, f32x4{0,0,0,0}};
#pragma unroll
    for (int kt = 0; kt < 2; ++kt)
#pragma unroll
        for (int c = 0; c < 4; ++c) {
            const short8 b = *(const short8*)&Kb[(16 * c + row16) * TS + quad * 8 + 32 * kt];
            accA[c] = __builtin_amdgcn_mfma_f32_16x16x32_bf16(aq[kt], b, accA[c], 0, 0, 0);
        }

    // Z numerator: accZ[r] = phiQ(row).kpref, identical in every lane column
    f32x4 accZ = f32x4{0, 0, 0, 0};
    accZ = __builtin_amdgcn_mfma_f32_16x16x32_bf16(aq[0], bZhi0, accZ, 0, 0, 0);
    accZ = __builtin_amdgcn_mfma_f32_16x16x32_bf16(aq[1], bZhi1, accZ, 0, 0, 0);
    accZ = __builtin_amdgcn_mfma_f32_16x16x32_bf16(aq[0], bZlo0, accZ, 0, 0, 0);
    accZ = __builtin_amdgcn_mfma_f32_16x16x32_bf16(aq[1], bZlo1, accZ, 0, 0, 0);

    // causal mask + in-register rowsums
    float rs[4] = {0.f, 0.f, 0.f, 0.f};
#pragma unroll
    for (int c = 0; c < 4; ++c)
#pragma unroll
        for (int r = 0; r < 4; ++r) {
            const int row = 16 * w + quad * 4 + r;
            const int col = 16 * c + row16;
            const float v = (col <= row) ? accA[c][r] : 0.f;
            accA[c][r] = v;
            rs[r] += v;
        }
#pragma unroll
    for (int off = 1; off < 16; off <<= 1)
#pragma unroll
        for (int r = 0; r < 4; ++r)
            rs[r] += __shfl_xor(rs[r], off, 64);

    __syncthreads();   // all Kb reads (QK^T) done before overwrite with A

    // write A (bf16) into Kb slab (intra-wave write->read: rows 16w..16w+15)
#pragma unroll
    for (int c = 0; c < 4; ++c)
#pragma unroll
        for (int r = 0; r < 4; ++r)
            Kb[(16 * w + quad * 4 + r) * TS + 16 * c + row16] = f2bf(accA[c][r]);

    // St regs -> LDS
    *(short8*)&St[m0 * TS + dg0] = s0;
    *(short8*)&St[m1 * TS + dg1] = s1;
    __syncthreads();   // St visible block-wide

    // out = (A @ V + Q @ Sp) * Z
    f32x4 accO[4] = {f32x4{0,0,0,0}, f32x4{0,0,0,0}, f32x4{0,0,0,0}, f32x4{0,0,0,0}};
#pragma unroll
    for (int kt = 0; kt < 2; ++kt) {
        const short8 aA = *(const short8*)&Kb[(16 * w + row16) * TS + quad * 8 + 32 * kt];
#pragma unroll
        for (int c = 0; c < 4; ++c) {
            const short8 bV = *(const short8*)&Vt[(16 * c + row16) * TS + quad * 8 + 32 * kt];
            accO[c] = __builtin_amdgcn_mfma_f32_16x16x32_bf16(aA, bV, accO[c], 0, 0, 0);
        }
#pragma unroll
        for (int c = 0; c < 4; ++c) {
            const short8 bS = *(const short8*)&St[(16 * c + row16) * TS + quad * 8 + 32 * kt];
            accO[c] = __builtin_amdgcn_mfma_f32_16x16x32_bf16(aq[kt], bS, accO[c], 0, 0, 0);
        }
    }

#pragma unroll
    for (int r = 0; r < 4; ++r) {
        const int row = 16 * w + quad * 4 + r;
        const float z = 1.0f / (accZ[r] + rs[r] + EPS_);
        const size_t ob = ((size_t)(n * L_ + g * C + row) * H_ + h) * M_;
#pragma unroll
        for (int c = 0; c < 4; ++c)
            out[ob + 16 * c + row16] = accO[c][r] * z;
    }
}

extern "C" void kernel_launch(void* const* d_in, const int* in_sizes, int n_in,
                              void* d_out, int out_size, void* d_ws, size_t ws_size,
                              hipStream_t stream) {
    const float* q = (const float*)d_in[0];
    const float* k = (const float*)d_in[1];
    const float* v = (const float*)d_in[2];
    float* out = (float*)d_out;
    unsigned short* wsSb = (unsigned short*)d_ws;            // NH*G*D*M bf16 (4 MB)
    float* wsK = (float*)((char*)d_ws + (size_t)NH * G * D_ * M_ * 2);  // fp32 128 KB

    k_fused<<<dim3(NBLK), dim3(256), 0, stream>>>(q, k, v, out, wsSb, wsK);
}

// Round 3
// 85.337 us; speedup vs baseline: 3.1256x; 3.1256x over previous
//
#include <hip/hip_runtime.h>

// Causal linear attention (elu+1 feature map), chunked-scan formulation.
// Shapes fixed by the reference: N=2, L=2048, H=8, D=64, M=64, fp32.
//
// R14: revert of R13's single-kernel grid-barrier fusion, which regressed
// 84.5 -> 266us (steady-state 214us at 0.2% MfmaUtil: 512 blocks spinning on
// one device-scope atomic across 8 non-coherent XCD L2s costs far more than
// the two launch boundaries it replaced; one 32ms outlier under rocprof).
// Structure = R12 (best measured, 84.5us):
//   k_chunksum (bf16 MFMA, bf16 S^T aggregates) ->
//   k_scan (256x128, parallel exclusive prefix, packed bf16 pairs) ->
//   k_out (bf16 MFMA; Z via MFMA with column-constant kpref B-fragment,
//          bf16 hi+lo split; in-register rowsums; two barriers only).
// Budget at this point: ~44us harness ws-poison fill (fixed) + ~2us restores
// + ~38us kernels/gaps, with the kernels near their BW/latency floors.

namespace {
constexpr int N_ = 2, L_ = 2048, H_ = 8, D_ = 64, M_ = 64;
constexpr int C  = 64;            // chunk length
constexpr int G  = L_ / C;        // 32 chunks per sequence
constexpr int NH = N_ * H_;       // 16 independent (n,h) sequences
constexpr int LDH = H_ * D_;      // stride (floats) between consecutive l
constexpr int TS  = 72;           // bf16 LDS row stride
constexpr float EPS_ = 1e-6f;
}

typedef __attribute__((ext_vector_type(8))) short short8;
typedef __attribute__((ext_vector_type(4))) float f32x4;

__device__ __forceinline__ float phi(float x) {
    return x > 0.0f ? x + 1.0f : __expf(x);
}
__device__ __forceinline__ unsigned short f2bf(float x) {
    unsigned int u = __float_as_uint(x);
    u += 0x7fffu + ((u >> 16) & 1u);          // round-to-nearest-even
    return (unsigned short)(u >> 16);
}
__device__ __forceinline__ float bf2f(unsigned short h) {
    return __uint_as_float(((unsigned int)h) << 16);
}
__device__ __forceinline__ ushort4 pack4(float a, float b, float c, float d) {
    ushort4 p; p.x = f2bf(a); p.y = f2bf(b); p.z = f2bf(c); p.w = f2bf(d);
    return p;
}

// ---------------------------------------------------------------------------
// Kernel 1 (MFMA): S_chunk^T[m][d] (bf16, packed) and ksum[d] (fp32)
// ---------------------------------------------------------------------------
__global__ __launch_bounds__(256, 4) void k_chunksum(
    const float* __restrict__ keys, const float* __restrict__ values,
    unsigned short* __restrict__ wsSb, float* __restrict__ wsK)
{
    __shared__ __align__(16) unsigned short Kt[C * TS];
    __shared__ __align__(16) unsigned short Vt[C * TS];
    const int bid = blockIdx.x;
    const int g = bid % G, nh = bid / G;
    const int n = nh / H_, h = nh % H_;
    const int t = threadIdx.x;
    const size_t base = ((size_t)(n * L_ + g * C) * H_ + h) * D_;

    // stage with transpose scatter: Kt[d][j] = phi(K)^T, Vt[m][j] = V^T
#pragma unroll
    for (int r = 0; r < 4; ++r) {
        const int f = t + 256 * r;
        const int j = f >> 4, c = (f & 15) * 4;
        const size_t ga = base + (size_t)j * LDH + c;
        const float4 kv = *(const float4*)(keys + ga);
        const float4 vv = *(const float4*)(values + ga);
        Kt[(c + 0) * TS + j] = f2bf(phi(kv.x));
        Kt[(c + 1) * TS + j] = f2bf(phi(kv.y));
        Kt[(c + 2) * TS + j] = f2bf(phi(kv.z));
        Kt[(c + 3) * TS + j] = f2bf(phi(kv.w));
        Vt[(c + 0) * TS + j] = f2bf(vv.x);
        Vt[(c + 1) * TS + j] = f2bf(vv.y);
        Vt[(c + 2) * TS + j] = f2bf(vv.z);
        Vt[(c + 3) * TS + j] = f2bf(vv.w);
    }
    __syncthreads();

    const int w = t >> 6, lane = t & 63;
    const int row16 = lane & 15, quad = lane >> 4;

    f32x4 acc[4] = {f32x4{0,0,0,0}, f32x4{0,0,0,0}, f32x4{0,0,0,0}, f32x4{0,0,0,0}};
    f32x4 accK = f32x4{0,0,0,0};
    short8 ones;
#pragma unroll
    for (int i = 0; i < 8; ++i) ones[i] = (short)0x3F80;   // bf16(1.0)

#pragma unroll
    for (int kt = 0; kt < 2; ++kt) {
        const short8 a = *(const short8*)&Kt[(16 * w + row16) * TS + quad * 8 + 32 * kt];
#pragma unroll
        for (int c = 0; c < 4; ++c) {
            const short8 b = *(const short8*)&Vt[(16 * c + row16) * TS + quad * 8 + 32 * kt];
            acc[c] = __builtin_amdgcn_mfma_f32_16x16x32_bf16(a, b, acc[c], 0, 0, 0);
        }
        accK = __builtin_amdgcn_mfma_f32_16x16x32_bf16(a, ones, accK, 0, 0, 0);
    }

    // store transposed: S^T[m][d], d-run of 4 packed into one 8B write
    unsigned short* Sc = wsSb + (size_t)bid * (D_ * M_);
#pragma unroll
    for (int c = 0; c < 4; ++c) {
        *(ushort4*)(Sc + (16 * c + row16) * D_ + 16 * w + quad * 4) =
            pack4(acc[c][0], acc[c][1], acc[c][2], acc[c][3]);
    }

    if (row16 == 0) {
#pragma unroll
        for (int r = 0; r < 4; ++r)
            wsK[(size_t)bid * D_ + 16 * w + quad * 4 + r] = accK[r];
    }
}

// ---------------------------------------------------------------------------
// Kernel 2: exclusive prefix scan over chunks.
// S: bf16, 2 chains packed per uint per thread (fp32 running sums).
// ksum: fp32, one float per thread (blocks with q==0).
// 256 blocks x 128 threads: one block per CU.
// ---------------------------------------------------------------------------
__global__ __launch_bounds__(128) void k_scan(
    unsigned short* __restrict__ wsSb, float* __restrict__ wsK)
{
    const int bid = blockIdx.x;               // 256 blocks
    const int nh = bid >> 4, q = bid & 15;    // 16 blocks per nh
    const int t = threadIdx.x;                // 0..127

    unsigned int* base =
        (unsigned int*)(wsSb + (size_t)nh * G * (D_ * M_) + q * 256 + t * 2);
    float r0 = 0.f, r1 = 0.f;
#pragma unroll
    for (int g = 0; g < G; ++g) {
        unsigned int* p = base + (size_t)g * (D_ * M_ / 2);
        const unsigned int v = *p;
        const float v0 = bf2f((unsigned short)(v & 0xffffu));
        const float v1 = bf2f((unsigned short)(v >> 16));
        *p = ((unsigned int)f2bf(r1) << 16) | (unsigned int)f2bf(r0);
        r0 += v0; r1 += v1;
    }

    if (q == 0 && t < D_) {
        float rk = 0.f;
        float* kb = wsK + (size_t)nh * G * D_ + t;
#pragma unroll
        for (int g = 0; g < G; ++g) {
            float* p = kb + (size_t)g * D_;
            const float v = *p;
            *p = rk;
            rk += v;
        }
    }
}

// ---------------------------------------------------------------------------
// Kernel 3 (MFMA): A = tril(phiQ phiK^T); Z = 1/(phiQ.kp + rowsum(A) + eps);
// out = (A @ V + Q @ Sp) * Z.
// Z computed via MFMA with a column-constant B fragment (kpref, bf16 hi+lo
// split) -> no serial wave0 section, no Rs/Zs LDS, only two barriers.
// ---------------------------------------------------------------------------
__global__ __launch_bounds__(256, 4) void k_out(
    const float* __restrict__ queries, const float* __restrict__ keys,
    const float* __restrict__ values, float* __restrict__ out,
    const unsigned short* __restrict__ wsSb, const float* __restrict__ wsK)
{
    __shared__ __align__(16) unsigned short Qb[C * TS];
    __shared__ __align__(16) unsigned short Kb[C * TS];   // phi(K) -> A
    __shared__ __align__(16) unsigned short Vt[C * TS];
    __shared__ __align__(16) unsigned short St[C * TS];

    const int bid = blockIdx.x;
    const int g = bid % G, nh = bid / G;
    const int n = nh / H_, h = nh % H_;
    const int t = threadIdx.x;
    const size_t base = ((size_t)(n * L_ + g * C) * H_ + h) * D_;
    const unsigned short* Spb = wsSb + (size_t)bid * (D_ * M_);
    const float* kpref = wsK + (size_t)bid * D_;

    // ---- stage: Qb/Kb contiguous (packed stores), Vt transposed -----------
#pragma unroll
    for (int r = 0; r < 4; ++r) {
        const int f = t + 256 * r;
        const int row = f >> 4, c = (f & 15) * 4;
        const size_t ga = base + (size_t)row * LDH + c;
        const float4 qv = *(const float4*)(queries + ga);
        const float4 kv = *(const float4*)(keys + ga);
        const float4 vv = *(const float4*)(values + ga);
        *(ushort4*)&Qb[row * TS + c] = pack4(phi(qv.x), phi(qv.y), phi(qv.z), phi(qv.w));
        *(ushort4*)&Kb[row * TS + c] = pack4(phi(kv.x), phi(kv.y), phi(kv.z), phi(kv.w));
        Vt[(c + 0) * TS + row] = f2bf(vv.x);
        Vt[(c + 1) * TS + row] = f2bf(vv.y);
        Vt[(c + 2) * TS + row] = f2bf(vv.z);
        Vt[(c + 3) * TS + row] = f2bf(vv.w);
    }
    // St^T: straight bf16 copy (already transposed in ws)
#pragma unroll
    for (int r = 0; r < 2; ++r) {
        const int idx = t + 256 * r;              // 0..511
        const int m = idx >> 3, dg = (idx & 7) * 8;
        *(short8*)&St[m * TS + dg] = *(const short8*)(Spb + m * D_ + dg);
    }

    const int w = t >> 6, lane = t & 63;
    const int row16 = lane & 15, quad = lane >> 4;

    // ---- kpref B-fragments (column-constant): B[k][*] = kpref[k] ----------
    // fragment element i of kt-th tile is kpref[32*kt + quad*8 + i];
    // hi+lo bf16 split keeps fp32-grade precision through the bf16 MFMA.
    const float* kp0 = kpref + quad * 8;
    const float4 kfa = *(const float4*)(kp0);
    const float4 kfb = *(const float4*)(kp0 + 4);
    const float4 kfc = *(const float4*)(kp0 + 32);
    const float4 kfd = *(const float4*)(kp0 + 36);
    short8 bZhi0, bZhi1, bZlo0, bZlo1;
    {
        const float f0[8] = {kfa.x, kfa.y, kfa.z, kfa.w, kfb.x, kfb.y, kfb.z, kfb.w};
        const float f1[8] = {kfc.x, kfc.y, kfc.z, kfc.w, kfd.x, kfd.y, kfd.z, kfd.w};
#pragma unroll
        for (int i = 0; i < 8; ++i) {
            const unsigned short h0 = f2bf(f0[i]);
            bZhi0[i] = (short)h0;
            bZlo0[i] = (short)f2bf(f0[i] - bf2f(h0));
            const unsigned short h1 = f2bf(f1[i]);
            bZhi1[i] = (short)h1;
            bZlo1[i] = (short)f2bf(f1[i] - bf2f(h1));
        }
    }
    __syncthreads();

    // ---- QK^T: wave w -> rows 16w..16w+15, all 4 col-tiles ----------------
    short8 aq[2];
#pragma unroll
    for (int kt = 0; kt < 2; ++kt)
        aq[kt] = *(const short8*)&Qb[(16 * w + row16) * TS + quad * 8 + 32 * kt];

    f32x4 accA[4] = {f32x4{0,0,0,0}, f32x4{0,0,0,0}, f32x4{0,0,0,0}, f32x4{0,0,0,0}};
#pragma unroll
    for (int kt = 0; kt < 2; ++kt)
#pragma unroll
        for (int c = 0; c < 4; ++c) {
            const short8 b = *(const short8*)&Kb[(16 * c + row16) * TS + quad * 8 + 32 * kt];
            accA[c] = __builtin_amdgcn_mfma_f32_16x16x32_bf16(aq[kt], b, accA[c], 0, 0, 0);
        }

    // ---- Z numerator part: accZ[r] = phiQ(row).kpref, all lanes -----------
    f32x4 accZ = f32x4{0, 0, 0, 0};
    accZ = __builtin_amdgcn_mfma_f32_16x16x32_bf16(aq[0], bZhi0, accZ, 0, 0, 0);
    accZ = __builtin_amdgcn_mfma_f32_16x16x32_bf16(aq[1], bZhi1, accZ, 0, 0, 0);
    accZ = __builtin_amdgcn_mfma_f32_16x16x32_bf16(aq[0], bZlo0, accZ, 0, 0, 0);
    accZ = __builtin_amdgcn_mfma_f32_16x16x32_bf16(aq[1], bZlo1, accZ, 0, 0, 0);

    // ---- mask (causal) in fp32 + in-register rowsums ----------------------
    float rs[4] = {0.f, 0.f, 0.f, 0.f};
#pragma unroll
    for (int c = 0; c < 4; ++c)
#pragma unroll
        for (int r = 0; r < 4; ++r) {
            const int row = 16 * w + quad * 4 + r;
            const int col = 16 * c + row16;
            const float v = (col <= row) ? accA[c][r] : 0.f;
            accA[c][r] = v;
            rs[r] += v;
        }
#pragma unroll
    for (int off = 1; off < 16; off <<= 1)
#pragma unroll
        for (int r = 0; r < 4; ++r)
            rs[r] += __shfl_xor(rs[r], off, 64);
    // rs[r] now = full rowsum of row 16w+quad*4+r, held by every lane that
    // will scale that row's outputs. No LDS round-trip needed.

    __syncthreads();   // all Kb reads (QK^T) done before overwrite with A

    // ---- write A (bf16) into Kb slab --------------------------------------
    // wave w writes rows 16w..16w+15 and below reads back only those rows:
    // intra-wave LDS ordering, no block barrier required.
#pragma unroll
    for (int c = 0; c < 4; ++c)
#pragma unroll
        for (int r = 0; r < 4; ++r)
            Kb[(16 * w + quad * 4 + r) * TS + 16 * c + row16] = f2bf(accA[c][r]);

    // ---- out = (A @ V + Q @ Sp) * Z ---------------------------------------
    f32x4 accO[4] = {f32x4{0,0,0,0}, f32x4{0,0,0,0}, f32x4{0,0,0,0}, f32x4{0,0,0,0}};
#pragma unroll
    for (int kt = 0; kt < 2; ++kt) {
        const short8 aA = *(const short8*)&Kb[(16 * w + row16) * TS + quad * 8 + 32 * kt];
#pragma unroll
        for (int c = 0; c < 4; ++c) {
            const short8 bV = *(const short8*)&Vt[(16 * c + row16) * TS + quad * 8 + 32 * kt];
            accO[c] = __builtin_amdgcn_mfma_f32_16x16x32_bf16(aA, bV, accO[c], 0, 0, 0);
        }
#pragma unroll
        for (int c = 0; c < 4; ++c) {
            const short8 bS = *(const short8*)&St[(16 * c + row16) * TS + quad * 8 + 32 * kt];
            accO[c] = __builtin_amdgcn_mfma_f32_16x16x32_bf16(aq[kt], bS, accO[c], 0, 0, 0);
        }
    }

#pragma unroll
    for (int r = 0; r < 4; ++r) {
        const int row = 16 * w + quad * 4 + r;
        const float z = 1.0f / (accZ[r] + rs[r] + EPS_);
        const size_t ob = ((size_t)(n * L_ + g * C + row) * H_ + h) * M_;
#pragma unroll
        for (int c = 0; c < 4; ++c)
            out[ob + 16 * c + row16] = accO[c][r] * z;
    }
}

extern "C" void kernel_launch(void* const* d_in, const int* in_sizes, int n_in,
                              void* d_out, int out_size, void* d_ws, size_t ws_size,
                              hipStream_t stream) {
    const float* q = (const float*)d_in[0];
    const float* k = (const float*)d_in[1];
    const float* v = (const float*)d_in[2];
    float* out = (float*)d_out;
    unsigned short* wsSb = (unsigned short*)d_ws;            // NH*G*D*M bf16 (4 MB)
    float* wsK = (float*)((char*)d_ws + (size_t)NH * G * D_ * M_ * 2);  // fp32 128 KB

    k_chunksum<<<dim3(NH * G), dim3(256), 0, stream>>>(k, v, wsSb, wsK);
    k_scan<<<dim3(NH * 16), dim3(128), 0, stream>>>(wsSb, wsK);
    k_out<<<dim3(NH * G), dim3(256), 0, stream>>>(q, k, v, out, wsSb, wsK);
}

// Round 4
// 83.993 us; speedup vs baseline: 3.1757x; 1.0160x over previous
//
#include <hip/hip_runtime.h>

// Causal linear attention (elu+1 feature map), chunked-scan formulation.
// Shapes fixed by the reference: N=2, L=2048, H=8, D=64, M=64, fp32.
//
// R15 (from R14 @85.3us): k_scan restructured from 32 serial load->store
// round-trips per thread into gather-all(32 independent loads into regs) ->
// register prefix -> scatter-all. Guarantees the memory phase is one
// pipelined burst (~1 latency) instead of a 32-deep dependent chain the
// compiler may not have hoisted. Everything else = R12/R14 structure
// (best measured): k_chunksum (bf16 MFMA S^T + ksum) -> k_scan ->
// k_out (bf16 MFMA; Z via column-constant kpref MFMA, hi+lo split;
// in-register rowsums; two barriers).
// Budget: ~44us harness ws-poison fill (fixed) + ~2us restores + kernels.

namespace {
constexpr int N_ = 2, L_ = 2048, H_ = 8, D_ = 64, M_ = 64;
constexpr int C  = 64;            // chunk length
constexpr int G  = L_ / C;        // 32 chunks per sequence
constexpr int NH = N_ * H_;       // 16 independent (n,h) sequences
constexpr int LDH = H_ * D_;      // stride (floats) between consecutive l
constexpr int TS  = 72;           // bf16 LDS row stride
constexpr float EPS_ = 1e-6f;
}

typedef __attribute__((ext_vector_type(8))) short short8;
typedef __attribute__((ext_vector_type(4))) float f32x4;

__device__ __forceinline__ float phi(float x) {
    return x > 0.0f ? x + 1.0f : __expf(x);
}
__device__ __forceinline__ unsigned short f2bf(float x) {
    unsigned int u = __float_as_uint(x);
    u += 0x7fffu + ((u >> 16) & 1u);          // round-to-nearest-even
    return (unsigned short)(u >> 16);
}
__device__ __forceinline__ float bf2f(unsigned short h) {
    return __uint_as_float(((unsigned int)h) << 16);
}
__device__ __forceinline__ ushort4 pack4(float a, float b, float c, float d) {
    ushort4 p; p.x = f2bf(a); p.y = f2bf(b); p.z = f2bf(c); p.w = f2bf(d);
    return p;
}

// ---------------------------------------------------------------------------
// Kernel 1 (MFMA): S_chunk^T[m][d] (bf16, packed) and ksum[d] (fp32)
// ---------------------------------------------------------------------------
__global__ __launch_bounds__(256, 4) void k_chunksum(
    const float* __restrict__ keys, const float* __restrict__ values,
    unsigned short* __restrict__ wsSb, float* __restrict__ wsK)
{
    __shared__ __align__(16) unsigned short Kt[C * TS];
    __shared__ __align__(16) unsigned short Vt[C * TS];
    const int bid = blockIdx.x;
    const int g = bid % G, nh = bid / G;
    const int n = nh / H_, h = nh % H_;
    const int t = threadIdx.x;
    const size_t base = ((size_t)(n * L_ + g * C) * H_ + h) * D_;

    // stage with transpose scatter: Kt[d][j] = phi(K)^T, Vt[m][j] = V^T
#pragma unroll
    for (int r = 0; r < 4; ++r) {
        const int f = t + 256 * r;
        const int j = f >> 4, c = (f & 15) * 4;
        const size_t ga = base + (size_t)j * LDH + c;
        const float4 kv = *(const float4*)(keys + ga);
        const float4 vv = *(const float4*)(values + ga);
        Kt[(c + 0) * TS + j] = f2bf(phi(kv.x));
        Kt[(c + 1) * TS + j] = f2bf(phi(kv.y));
        Kt[(c + 2) * TS + j] = f2bf(phi(kv.z));
        Kt[(c + 3) * TS + j] = f2bf(phi(kv.w));
        Vt[(c + 0) * TS + j] = f2bf(vv.x);
        Vt[(c + 1) * TS + j] = f2bf(vv.y);
        Vt[(c + 2) * TS + j] = f2bf(vv.z);
        Vt[(c + 3) * TS + j] = f2bf(vv.w);
    }
    __syncthreads();

    const int w = t >> 6, lane = t & 63;
    const int row16 = lane & 15, quad = lane >> 4;

    f32x4 acc[4] = {f32x4{0,0,0,0}, f32x4{0,0,0,0}, f32x4{0,0,0,0}, f32x4{0,0,0,0}};
    f32x4 accK = f32x4{0,0,0,0};
    short8 ones;
#pragma unroll
    for (int i = 0; i < 8; ++i) ones[i] = (short)0x3F80;   // bf16(1.0)

#pragma unroll
    for (int kt = 0; kt < 2; ++kt) {
        const short8 a = *(const short8*)&Kt[(16 * w + row16) * TS + quad * 8 + 32 * kt];
#pragma unroll
        for (int c = 0; c < 4; ++c) {
            const short8 b = *(const short8*)&Vt[(16 * c + row16) * TS + quad * 8 + 32 * kt];
            acc[c] = __builtin_amdgcn_mfma_f32_16x16x32_bf16(a, b, acc[c], 0, 0, 0);
        }
        accK = __builtin_amdgcn_mfma_f32_16x16x32_bf16(a, ones, accK, 0, 0, 0);
    }

    // store transposed: S^T[m][d], d-run of 4 packed into one 8B write
    unsigned short* Sc = wsSb + (size_t)bid * (D_ * M_);
#pragma unroll
    for (int c = 0; c < 4; ++c) {
        *(ushort4*)(Sc + (16 * c + row16) * D_ + 16 * w + quad * 4) =
            pack4(acc[c][0], acc[c][1], acc[c][2], acc[c][3]);
    }

    if (row16 == 0) {
#pragma unroll
        for (int r = 0; r < 4; ++r)
            wsK[(size_t)bid * D_ + 16 * w + quad * 4 + r] = accK[r];
    }
}

// ---------------------------------------------------------------------------
// Kernel 2: exclusive prefix scan over chunks.
// Gather-all -> register prefix -> scatter-all: the 32 chunk elements of a
// chain are loaded as 32 INDEPENDENT loads into registers (one pipelined
// burst, ~1 L2/L3 latency total) instead of a 32-deep load->store->load
// serial chain. S: bf16 pairs packed per uint; ksum: fp32.
// 256 blocks x 128 threads: one block per CU.
// ---------------------------------------------------------------------------
__global__ __launch_bounds__(128) void k_scan(
    unsigned short* __restrict__ wsSb, float* __restrict__ wsK)
{
    const int bid = blockIdx.x;               // 256 blocks
    const int nh = bid >> 4, q = bid & 15;    // 16 blocks per nh
    const int t = threadIdx.x;                // 0..127

    unsigned int* base =
        (unsigned int*)(wsSb + (size_t)nh * G * (D_ * M_) + q * 256 + t * 2);

    // gather: 32 independent loads
    unsigned int v[G];
#pragma unroll
    for (int g = 0; g < G; ++g)
        v[g] = base[(size_t)g * (D_ * M_ / 2)];

    // register exclusive prefix + scatter
    float r0 = 0.f, r1 = 0.f;
#pragma unroll
    for (int g = 0; g < G; ++g) {
        const unsigned int vg = v[g];
        base[(size_t)g * (D_ * M_ / 2)] =
            ((unsigned int)f2bf(r1) << 16) | (unsigned int)f2bf(r0);
        r0 += bf2f((unsigned short)(vg & 0xffffu));
        r1 += bf2f((unsigned short)(vg >> 16));
    }

    if (q == 0 && t < D_) {
        float* kb = wsK + (size_t)nh * G * D_ + t;
        float kv[G];
#pragma unroll
        for (int g = 0; g < G; ++g)
            kv[g] = kb[(size_t)g * D_];
        float rk = 0.f;
#pragma unroll
        for (int g = 0; g < G; ++g) {
            kb[(size_t)g * D_] = rk;
            rk += kv[g];
        }
    }
}

// ---------------------------------------------------------------------------
// Kernel 3 (MFMA): A = tril(phiQ phiK^T); Z = 1/(phiQ.kp + rowsum(A) + eps);
// out = (A @ V + Q @ Sp) * Z.
// Z computed via MFMA with a column-constant B fragment (kpref, bf16 hi+lo
// split) -> no serial wave0 section, no Rs/Zs LDS, only two barriers.
// ---------------------------------------------------------------------------
__global__ __launch_bounds__(256, 4) void k_out(
    const float* __restrict__ queries, const float* __restrict__ keys,
    const float* __restrict__ values, float* __restrict__ out,
    const unsigned short* __restrict__ wsSb, const float* __restrict__ wsK)
{
    __shared__ __align__(16) unsigned short Qb[C * TS];
    __shared__ __align__(16) unsigned short Kb[C * TS];   // phi(K) -> A
    __shared__ __align__(16) unsigned short Vt[C * TS];
    __shared__ __align__(16) unsigned short St[C * TS];

    const int bid = blockIdx.x;
    const int g = bid % G, nh = bid / G;
    const int n = nh / H_, h = nh % H_;
    const int t = threadIdx.x;
    const size_t base = ((size_t)(n * L_ + g * C) * H_ + h) * D_;
    const unsigned short* Spb = wsSb + (size_t)bid * (D_ * M_);
    const float* kpref = wsK + (size_t)bid * D_;

    // ---- stage: Qb/Kb contiguous (packed stores), Vt transposed -----------
#pragma unroll
    for (int r = 0; r < 4; ++r) {
        const int f = t + 256 * r;
        const int row = f >> 4, c = (f & 15) * 4;
        const size_t ga = base + (size_t)row * LDH + c;
        const float4 qv = *(const float4*)(queries + ga);
        const float4 kv = *(const float4*)(keys + ga);
        const float4 vv = *(const float4*)(values + ga);
        *(ushort4*)&Qb[row * TS + c] = pack4(phi(qv.x), phi(qv.y), phi(qv.z), phi(qv.w));
        *(ushort4*)&Kb[row * TS + c] = pack4(phi(kv.x), phi(kv.y), phi(kv.z), phi(kv.w));
        Vt[(c + 0) * TS + row] = f2bf(vv.x);
        Vt[(c + 1) * TS + row] = f2bf(vv.y);
        Vt[(c + 2) * TS + row] = f2bf(vv.z);
        Vt[(c + 3) * TS + row] = f2bf(vv.w);
    }
    // St^T: straight bf16 copy (already transposed in ws)
#pragma unroll
    for (int r = 0; r < 2; ++r) {
        const int idx = t + 256 * r;              // 0..511
        const int m = idx >> 3, dg = (idx & 7) * 8;
        *(short8*)&St[m * TS + dg] = *(const short8*)(Spb + m * D_ + dg);
    }

    const int w = t >> 6, lane = t & 63;
    const int row16 = lane & 15, quad = lane >> 4;

    // ---- kpref B-fragments (column-constant): B[k][*] = kpref[k] ----------
    // fragment element i of kt-th tile is kpref[32*kt + quad*8 + i];
    // hi+lo bf16 split keeps fp32-grade precision through the bf16 MFMA.
    const float* kp0 = kpref + quad * 8;
    const float4 kfa = *(const float4*)(kp0);
    const float4 kfb = *(const float4*)(kp0 + 4);
    const float4 kfc = *(const float4*)(kp0 + 32);
    const float4 kfd = *(const float4*)(kp0 + 36);
    short8 bZhi0, bZhi1, bZlo0, bZlo1;
    {
        const float f0[8] = {kfa.x, kfa.y, kfa.z, kfa.w, kfb.x, kfb.y, kfb.z, kfb.w};
        const float f1[8] = {kfc.x, kfc.y, kfc.z, kfc.w, kfd.x, kfd.y, kfd.z, kfd.w};
#pragma unroll
        for (int i = 0; i < 8; ++i) {
            const unsigned short h0 = f2bf(f0[i]);
            bZhi0[i] = (short)h0;
            bZlo0[i] = (short)f2bf(f0[i] - bf2f(h0));
            const unsigned short h1 = f2bf(f1[i]);
            bZhi1[i] = (short)h1;
            bZlo1[i] = (short)f2bf(f1[i] - bf2f(h1));
        }
    }
    __syncthreads();

    // ---- QK^T: wave w -> rows 16w..16w+15, all 4 col-tiles ----------------
    short8 aq[2];
#pragma unroll
    for (int kt = 0; kt < 2; ++kt)
        aq[kt] = *(const short8*)&Qb[(16 * w + row16) * TS + quad * 8 + 32 * kt];

    f32x4 accA[4] = {f32x4{0,0,0,0}, f32x4{0,0,0,0}, f32x4{0,0,0,0}, f32x4{0,0,0,0}};
#pragma unroll
    for (int kt = 0; kt < 2; ++kt)
#pragma unroll
        for (int c = 0; c < 4; ++c) {
            const short8 b = *(const short8*)&Kb[(16 * c + row16) * TS + quad * 8 + 32 * kt];
            accA[c] = __builtin_amdgcn_mfma_f32_16x16x32_bf16(aq[kt], b, accA[c], 0, 0, 0);
        }

    // ---- Z numerator part: accZ[r] = phiQ(row).kpref, all lanes -----------
    f32x4 accZ = f32x4{0, 0, 0, 0};
    accZ = __builtin_amdgcn_mfma_f32_16x16x32_bf16(aq[0], bZhi0, accZ, 0, 0, 0);
    accZ = __builtin_amdgcn_mfma_f32_16x16x32_bf16(aq[1], bZhi1, accZ, 0, 0, 0);
    accZ = __builtin_amdgcn_mfma_f32_16x16x32_bf16(aq[0], bZlo0, accZ, 0, 0, 0);
    accZ = __builtin_amdgcn_mfma_f32_16x16x32_bf16(aq[1], bZlo1, accZ, 0, 0, 0);

    // ---- mask (causal) in fp32 + in-register rowsums ----------------------
    float rs[4] = {0.f, 0.f, 0.f, 0.f};
#pragma unroll
    for (int c = 0; c < 4; ++c)
#pragma unroll
        for (int r = 0; r < 4; ++r) {
            const int row = 16 * w + quad * 4 + r;
            const int col = 16 * c + row16;
            const float v = (col <= row) ? accA[c][r] : 0.f;
            accA[c][r] = v;
            rs[r] += v;
        }
#pragma unroll
    for (int off = 1; off < 16; off <<= 1)
#pragma unroll
        for (int r = 0; r < 4; ++r)
            rs[r] += __shfl_xor(rs[r], off, 64);
    // rs[r] now = full rowsum of row 16w+quad*4+r, held by every lane that
    // will scale that row's outputs. No LDS round-trip needed.

    __syncthreads();   // all Kb reads (QK^T) done before overwrite with A

    // ---- write A (bf16) into Kb slab --------------------------------------
    // wave w writes rows 16w..16w+15 and below reads back only those rows:
    // intra-wave LDS ordering, no block barrier required.
#pragma unroll
    for (int c = 0; c < 4; ++c)
#pragma unroll
        for (int r = 0; r < 4; ++r)
            Kb[(16 * w + quad * 4 + r) * TS + 16 * c + row16] = f2bf(accA[c][r]);

    // ---- out = (A @ V + Q @ Sp) * Z ---------------------------------------
    f32x4 accO[4] = {f32x4{0,0,0,0}, f32x4{0,0,0,0}, f32x4{0,0,0,0}, f32x4{0,0,0,0}};
#pragma unroll
    for (int kt = 0; kt < 2; ++kt) {
        const short8 aA = *(const short8*)&Kb[(16 * w + row16) * TS + quad * 8 + 32 * kt];
#pragma unroll
        for (int c = 0; c < 4; ++c) {
            const short8 bV = *(const short8*)&Vt[(16 * c + row16) * TS + quad * 8 + 32 * kt];
            accO[c] = __builtin_amdgcn_mfma_f32_16x16x32_bf16(aA, bV, accO[c], 0, 0, 0);
        }
#pragma unroll
        for (int c = 0; c < 4; ++c) {
            const short8 bS = *(const short8*)&St[(16 * c + row16) * TS + quad * 8 + 32 * kt];
            accO[c] = __builtin_amdgcn_mfma_f32_16x16x32_bf16(aq[kt], bS, accO[c], 0, 0, 0);
        }
    }

#pragma unroll
    for (int r = 0; r < 4; ++r) {
        const int row = 16 * w + quad * 4 + r;
        const float z = 1.0f / (accZ[r] + rs[r] + EPS_);
        const size_t ob = ((size_t)(n * L_ + g * C + row) * H_ + h) * M_;
#pragma unroll
        for (int c = 0; c < 4; ++c)
            out[ob + 16 * c + row16] = accO[c][r] * z;
    }
}

extern "C" void kernel_launch(void* const* d_in, const int* in_sizes, int n_in,
                              void* d_out, int out_size, void* d_ws, size_t ws_size,
                              hipStream_t stream) {
    const float* q = (const float*)d_in[0];
    const float* k = (const float*)d_in[1];
    const float* v = (const float*)d_in[2];
    float* out = (float*)d_out;
    unsigned short* wsSb = (unsigned short*)d_ws;            // NH*G*D*M bf16 (4 MB)
    float* wsK = (float*)((char*)d_ws + (size_t)NH * G * D_ * M_ * 2);  // fp32 128 KB

    k_chunksum<<<dim3(NH * G), dim3(256), 0, stream>>>(k, v, wsSb, wsK);
    k_scan<<<dim3(NH * 16), dim3(128), 0, stream>>>(wsSb, wsK);
    k_out<<<dim3(NH * G), dim3(256), 0, stream>>>(q, k, v, out, wsSb, wsK);
}